// Round 1
// baseline (668.291 us; speedup 1.0000x reference)
//
#include <hip/hip_runtime.h>
#include <hip/hip_bf16.h>

#define BSZ 2
#define LLEN 2048
#define NHEADS 32
#define HEADDIM 64
#define DSTATE 128
#define DCONV 4
#define DINNER (NHEADS * HEADDIM)                  // 2048
#define DPROJ  (2 * DINNER + 2 * DSTATE + NHEADS)  // 4384
#define Q 256                                      // scan chunk length
#define NCHUNK (LLEN / Q)                          // 8

__device__ __forceinline__ float sigm(float x) {
    // v_exp + v_rcp (approx rcp, ~1 ulp) — avoids IEEE-div Newton steps
    return __builtin_amdgcn_rcpf(1.0f + __expf(-x));
}

// Robust python-int scalar read (int32 bits or float32 bits).
__device__ __forceinline__ float int_scalar(const int* p) {
    int i = *p;
    if (i >= 0 && i <= 1000000) return (float)i;
    return __int_as_float(i);
}

// ---------------------------------------------------------------------------
// Kernel 1: B/C conv channels + dt/dA into fp32 workspace.
// ---------------------------------------------------------------------------
__global__ __launch_bounds__(256) void pre_kernel(
    const float* __restrict__ zx, const float* __restrict__ cw,
    const float* __restrict__ cb, const float* __restrict__ dtb,
    const float* __restrict__ alog, const float* __restrict__ dts,
    const int* __restrict__ mn_p, const int* __restrict__ mx_p,
    float* __restrict__ Bc, float* __restrict__ Cc,
    float2* __restrict__ dtA)
{
    const int bl  = blockIdx.x;            // 0 .. B*L-1
    const int b   = bl / LLEN;
    const int l   = bl % LLEN;
    const int tid = threadIdx.x;           // 0..255 == 2*DSTATE channels

    {
        const int c = DINNER + tid;        // conv channel (B/C region)
        float acc = cb[c];
        #pragma unroll
        for (int k = 0; k < DCONV; k++) {
            int lk = l - (DCONV - 1) + k;
            if (lk >= 0) {
                acc += cw[(size_t)c * DCONV + k] *
                       zx[((size_t)b * LLEN + lk) * DPROJ + DINNER + c];
            }
        }
        float v = acc * sigm(acc);
        if (tid < DSTATE) Bc[(size_t)bl * DSTATE + tid] = v;
        else              Cc[(size_t)bl * DSTATE + (tid - DSTATE)] = v;
    }

    if (tid < NHEADS) {
        float raw = zx[(size_t)bl * DPROJ + (DPROJ - NHEADS) + tid];
        float v   = raw * dts[tid] + dtb[tid];
        float sp  = (v > 20.0f) ? v : log1pf(__expf(v));
        float dt  = fminf(fmaxf(sp, int_scalar(mn_p)), int_scalar(mx_p));
        float A   = -__expf(alog[tid]);
        dtA[(size_t)bl * NHEADS + tid] = make_float2(dt, __expf(dt * A));
    }
}

// ---------------------------------------------------------------------------
// Kernel 2: per-chunk inclusive decay cumprod cumA[t] and chunk totals dtot.
// Grid (NCHUNK, NHEADS, BSZ) x 64. Lane owns 4 consecutive t.
// ---------------------------------------------------------------------------
__global__ __launch_bounds__(64) void cum_kernel(
    const float2* __restrict__ dtA, float* __restrict__ cumA,
    float* __restrict__ dtot)
{
    const int c = blockIdx.x, h = blockIdx.y, b = blockIdx.z;
    const int lane = threadIdx.x;          // 0..63
    const float2* pd = dtA + ((size_t)(b * LLEN + c * Q + lane * 4)) * NHEADS + h;
    const float a0 = pd[0].y;
    const float a1 = pd[NHEADS].y;
    const float a2 = pd[2 * NHEADS].y;
    const float a3 = pd[3 * NHEADS].y;

    float s = a0 * a1 * a2 * a3;           // per-lane product
    #pragma unroll
    for (int off = 1; off < 64; off <<= 1) {       // inclusive Hillis-Steele
        float v = __shfl_up(s, off, 64);
        if (lane >= off) s *= v;
    }
    float excl = __shfl_up(s, 1, 64);
    if (lane == 0) excl = 1.0f;

    const float c0 = excl * a0, c1 = c0 * a1, c2 = c1 * a2, c3 = c2 * a3;
    float* pc = cumA + ((size_t)(b * NHEADS + h) * NCHUNK + c) * Q + lane * 4;
    *(float4*)pc = make_float4(c0, c1, c2, c3);
    if (lane == 63) dtot[(size_t)(b * NHEADS + h) * NCHUNK + c] = c3;
}

// ---------------------------------------------------------------------------
// Phase A: single scan pass per chunk with ZERO initial state.
// Emits: ungated local outputs y_pre = y_local + D*xv (into `out`),
//        end-of-chunk local states SA.
// Grid (4*NCHUNK, 32, 2) x 256. Wave owns 4 p; lane=(ng<<2)|pidx; 8 n/lane.
// ---------------------------------------------------------------------------
__global__ __launch_bounds__(256, 4) void scan_kernel(
    const float* __restrict__ zx, const float* __restrict__ cw,
    const float* __restrict__ cb,
    const float* __restrict__ Bc, const float* __restrict__ Cc,
    const float2* __restrict__ dtA, const float* __restrict__ d_param,
    float* __restrict__ SA, float* __restrict__ ypre)
{
    const int pb   = blockIdx.x & 3;
    const int c    = blockIdx.x >> 2;    // chunk
    const int h    = blockIdx.y;
    const int b    = blockIdx.z;
    const int tid  = threadIdx.x;
    const int wave = tid >> 6;
    const int lane = tid & 63;
    const int p    = pb * 16 + wave * 4 + (lane & 3);
    const int ng   = lane >> 2;
    const int n0   = ng * 8;
    const int t0   = c * Q;

    const int cx = h * HEADDIM + p;
    const float w0 = cw[(size_t)cx * DCONV + 0];
    const float w1 = cw[(size_t)cx * DCONV + 1];
    const float w2 = cw[(size_t)cx * DCONV + 2];
    const float w3 = cw[(size_t)cx * DCONV + 3];
    const float bx = cb[cx];
    const float Dh = d_param[h];

    const float*  pB = Bc  + ((size_t)b * LLEN + t0) * DSTATE + n0;
    const float*  pC = Cc  + ((size_t)b * LLEN + t0) * DSTATE + n0;
    const float*  px = zx  + ((size_t)b * LLEN + t0) * DPROJ + DINNER + cx;
    const float2* pd = dtA + ((size_t)b * LLEN + t0) * NHEADS + h;
    float*        po = ypre + ((size_t)b * LLEN + t0) * DINNER + cx;

    // conv history entering the chunk
    float xh0 = 0.0f, xh1 = 0.0f, xh2 = 0.0f;
    if (c > 0) {
        xh0 = px[-(3 * DPROJ)];
        xh1 = px[-(2 * DPROJ)];
        xh2 = px[-(1 * DPROJ)];
    }

    float st[8];
    #pragma unroll
    for (int j = 0; j < 8; j++) st[j] = 0.0f;

    // depth-2 ring, pure pointer-increment addressing (no clamps)
    float4 rb0[2], rb1[2], rc0[2], rc1[2]; float rxv[2]; float2 rda[2];
    #pragma unroll
    for (int u = 0; u < 2; u++) {
        rb0[u] = *(const float4*)(pB + (size_t)u * DSTATE);
        rb1[u] = *(const float4*)(pB + (size_t)u * DSTATE + 4);
        rc0[u] = *(const float4*)(pC + (size_t)u * DSTATE);
        rc1[u] = *(const float4*)(pC + (size_t)u * DSTATE + 4);
        rxv[u] = px[(size_t)u * DPROJ];
        rda[u] = pd[(size_t)u * NHEADS];
    }
    const float*  pBn = pB + 2 * DSTATE;     // prefetch ptrs (t+2)
    const float*  pCn = pC + 2 * DSTATE;
    const float*  pxn = px + 2 * DPROJ;
    const float2* pdn = pd + 2 * NHEADS;
    float*        pw  = po;                  // write ptr (t)

    auto step = [&](int u, bool pf) {
        const float4 b0 = rb0[u], b1 = rb1[u];
        const float4 c0 = rc0[u], c1 = rc1[u];
        const float  xraw = rxv[u];
        const float2 da   = rda[u];
        if (pf) {
            rb0[u] = *(const float4*)(pBn + (size_t)u * DSTATE);
            rb1[u] = *(const float4*)(pBn + (size_t)u * DSTATE + 4);
            rc0[u] = *(const float4*)(pCn + (size_t)u * DSTATE);
            rc1[u] = *(const float4*)(pCn + (size_t)u * DSTATE + 4);
            rxv[u] = pxn[(size_t)u * DPROJ];
            rda[u] = pdn[(size_t)u * NHEADS];
        }
        const float cv = bx + w0 * xh0 + w1 * xh1 + w2 * xh2 + w3 * xraw;
        const float xv = cv * sigm(cv);
        const float coef = da.x * xv;
        const float dAv  = da.y;

        const float Bv[8] = {b0.x, b0.y, b0.z, b0.w, b1.x, b1.y, b1.z, b1.w};
        const float Cv[8] = {c0.x, c0.y, c0.z, c0.w, c1.x, c1.y, c1.z, c1.w};
        float acc0 = 0.0f, acc1 = 0.0f;
        #pragma unroll
        for (int j = 0; j < 4; j++) {
            st[j] = dAv * st[j] + coef * Bv[j];
            acc0 += st[j] * Cv[j];
        }
        #pragma unroll
        for (int j = 4; j < 8; j++) {
            st[j] = dAv * st[j] + coef * Bv[j];
            acc1 += st[j] * Cv[j];
        }
        float acc = acc0 + acc1;
        acc += __shfl_xor(acc, 4, 64);
        acc += __shfl_xor(acc, 8, 64);
        acc += __shfl_xor(acc, 16, 64);
        acc += __shfl_xor(acc, 32, 64);

        if (ng == 0) pw[(size_t)u * DINNER] = acc + Dh * xv;  // ungated y_pre

        xh0 = xh1; xh1 = xh2; xh2 = xraw;
    };

    for (int tb = 0; tb < Q - 2; tb += 2) {
        step(0, true);
        step(1, true);
        pBn += 2 * DSTATE; pCn += 2 * DSTATE;
        pxn += 2 * DPROJ;  pdn += 2 * NHEADS;
        pw  += 2 * DINNER;
    }
    step(0, false);   // t = Q-2
    step(1, false);   // t = Q-1

    const size_t sbase = ((size_t)(b * NHEADS + h) * NCHUNK + c) * HEADDIM * DSTATE
                       + (size_t)p * DSTATE + n0;
    *(float4*)(SA + sbase)     = make_float4(st[0], st[1], st[2], st[3]);
    *(float4*)(SA + sbase + 4) = make_float4(st[4], st[5], st[6], st[7]);
}

// ---------------------------------------------------------------------------
// Phase B: sequential chunk combine per (b,h). SA[c] := state ENTERING chunk c.
// ---------------------------------------------------------------------------
__global__ __launch_bounds__(256) void combine_kernel(
    const float* __restrict__ init_state, const float* __restrict__ dtot,
    float* __restrict__ SA)
{
    const int h = blockIdx.x, b = blockIdx.y, tid = threadIdx.x;
    const size_t hd = (size_t)(b * NHEADS + h);
    const size_t eb = (size_t)tid * 32;            // 32 elems per thread

    float4 run[8];
    const float4* pi = (const float4*)(init_state + hd * HEADDIM * DSTATE + eb);
    #pragma unroll
    for (int k = 0; k < 8; k++) run[k] = pi[k];

    for (int c = 0; c < NCHUNK; c++) {
        const float d = dtot[hd * NCHUNK + c];
        float4* ps = (float4*)(SA + (hd * NCHUNK + c) * HEADDIM * DSTATE + eb);
        #pragma unroll
        for (int k = 0; k < 8; k++) {
            float4 loc = ps[k];
            float4 sin = run[k];
            ps[k] = sin;                            // state entering chunk c
            run[k].x = d * sin.x + loc.x;
            run[k].y = d * sin.y + loc.y;
            run[k].z = d * sin.z + loc.z;
            run[k].w = d * sin.w + loc.w;
        }
    }
}

// ---------------------------------------------------------------------------
// Phase C: add entering-state contribution and apply silu(z) gate, in-place.
//   out[t,p] = (y_pre[t,p] + cumA[t] * sum_n C[t,n]*Sin[p,n]) * silu(z[t,p])
// Same lane decomposition as scan_kernel; no recurrence, no conv.
// ---------------------------------------------------------------------------
__global__ __launch_bounds__(256, 4) void gate_kernel(
    const float* __restrict__ zx, const float* __restrict__ Cc,
    const float* __restrict__ cumA, const float* __restrict__ SA,
    float* __restrict__ out)
{
    const int pb   = blockIdx.x & 3;
    const int c    = blockIdx.x >> 2;
    const int h    = blockIdx.y;
    const int b    = blockIdx.z;
    const int tid  = threadIdx.x;
    const int wave = tid >> 6;
    const int lane = tid & 63;
    const int p    = pb * 16 + wave * 4 + (lane & 3);
    const int ng   = lane >> 2;
    const int n0   = ng * 8;
    const int t0   = c * Q;
    const int cx   = h * HEADDIM + p;

    const float* pC  = Cc + ((size_t)b * LLEN + t0) * DSTATE + n0;
    const float* pz  = zx + ((size_t)b * LLEN + t0) * DPROJ + cx;
    const float* pcm = cumA + ((size_t)(b * NHEADS + h) * NCHUNK + c) * Q;
    float*       po  = out + ((size_t)b * LLEN + t0) * DINNER + cx;

    // entering state fragment (after combine)
    float st[8];
    {
        const size_t sbase = ((size_t)(b * NHEADS + h) * NCHUNK + c) * HEADDIM * DSTATE
                           + (size_t)p * DSTATE + n0;
        float4 s0 = *(const float4*)(SA + sbase);
        float4 s1 = *(const float4*)(SA + sbase + 4);
        st[0]=s0.x; st[1]=s0.y; st[2]=s0.z; st[3]=s0.w;
        st[4]=s1.x; st[5]=s1.y; st[6]=s1.z; st[7]=s1.w;
    }

    float4 rc0[2], rc1[2]; float rz[2], rcm[2], ry[2];
    #pragma unroll
    for (int u = 0; u < 2; u++) {
        rc0[u] = *(const float4*)(pC + (size_t)u * DSTATE);
        rc1[u] = *(const float4*)(pC + (size_t)u * DSTATE + 4);
        rz[u]  = pz[(size_t)u * DPROJ];
        rcm[u] = pcm[u];
        ry[u]  = po[(size_t)u * DINNER];
    }
    const float* pCn  = pC + 2 * DSTATE;
    const float* pzn  = pz + 2 * DPROJ;
    const float* pcn  = pcm + 2;
    const float* pyn  = po + 2 * DINNER;   // prefetch read (t+2)
    float*       pw   = po;                // write (t)

    auto step = [&](int u, bool pf) {
        const float4 c0 = rc0[u], c1 = rc1[u];
        const float  zraw = rz[u];
        const float  cum  = rcm[u];
        const float  yp   = ry[u];
        if (pf) {
            rc0[u] = *(const float4*)(pCn + (size_t)u * DSTATE);
            rc1[u] = *(const float4*)(pCn + (size_t)u * DSTATE + 4);
            rz[u]  = pzn[(size_t)u * DPROJ];
            rcm[u] = pcn[u];
            ry[u]  = pyn[(size_t)u * DINNER];
        }
        float acc = st[0]*c0.x + st[1]*c0.y + st[2]*c0.z + st[3]*c0.w
                  + st[4]*c1.x + st[5]*c1.y + st[6]*c1.z + st[7]*c1.w;
        acc += __shfl_xor(acc, 4, 64);
        acc += __shfl_xor(acc, 8, 64);
        acc += __shfl_xor(acc, 16, 64);
        acc += __shfl_xor(acc, 32, 64);
        if (ng == 0) {
            const float y  = yp + cum * acc;
            const float zg = zraw * sigm(zraw);
            pw[(size_t)u * DINNER] = y * zg;
        }
    };

    for (int tb = 0; tb < Q - 2; tb += 2) {
        step(0, true);
        step(1, true);
        pCn += 2 * DSTATE; pzn += 2 * DPROJ;
        pcn += 2; pyn += 2 * DINNER; pw += 2 * DINNER;
    }
    step(0, false);
    step(1, false);
}

// ---------------------------------------------------------------------------
extern "C" void kernel_launch(void* const* d_in, const int* in_sizes, int n_in,
                              void* d_out, int out_size, void* d_ws, size_t ws_size,
                              hipStream_t stream) {
    const float* zxbcdt   = (const float*)d_in[0];
    const float* conv_w   = (const float*)d_in[1];
    const float* conv_b   = (const float*)d_in[2];
    const float* dt_bias  = (const float*)d_in[3];
    const float* a_log    = (const float*)d_in[4];
    const float* d_param  = (const float*)d_in[5];
    const float* dt_scale = (const float*)d_in[6];
    const float* init_st  = (const float*)d_in[7];
    const int* dt_min_p   = (const int*)d_in[11];
    const int* dt_max_p   = (const int*)d_in[12];
    float* out = (float*)d_out;

    // workspace: 2 + 2 + 1 + 16.8 + 0.5 MiB + 2 KB ~= 22.3 MiB
    char* ws = (char*)d_ws;
    const size_t n_bl = (size_t)BSZ * LLEN;                          // 4096
    float*  Bc  = (float*)ws;  ws += n_bl * DSTATE * sizeof(float);  // 2 MiB
    float*  Cc  = (float*)ws;  ws += n_bl * DSTATE * sizeof(float);  // 2 MiB
    float2* dtA = (float2*)ws; ws += n_bl * NHEADS * sizeof(float2); // 1 MiB
    float*  SA  = (float*)ws;                                        // 16.8 MiB
    ws += (size_t)BSZ * NHEADS * NCHUNK * HEADDIM * DSTATE * sizeof(float);
    float*  dtot = (float*)ws; ws += (size_t)BSZ * NHEADS * NCHUNK * sizeof(float);
    float*  cumA = (float*)ws;                                       // 0.5 MiB
    ws += (size_t)BSZ * NHEADS * LLEN * sizeof(float);

    pre_kernel<<<dim3((unsigned)n_bl), 256, 0, stream>>>(
        zxbcdt, conv_w, conv_b, dt_bias, a_log, dt_scale,
        dt_min_p, dt_max_p, Bc, Cc, dtA);

    cum_kernel<<<dim3(NCHUNK, NHEADS, BSZ), 64, 0, stream>>>(dtA, cumA, dtot);

    scan_kernel<<<dim3(4 * NCHUNK, NHEADS, BSZ), 256, 0, stream>>>(
        zxbcdt, conv_w, conv_b, Bc, Cc, dtA, d_param, SA, out);

    combine_kernel<<<dim3(NHEADS, BSZ), 256, 0, stream>>>(init_st, dtot, SA);

    gate_kernel<<<dim3(4 * NCHUNK, NHEADS, BSZ), 256, 0, stream>>>(
        zxbcdt, Cc, cumA, SA, out);
}

// Round 2
// 496.203 us; speedup vs baseline: 1.3468x; 1.3468x over previous
//
#include <hip/hip_runtime.h>
#include <hip/hip_bf16.h>

#define BSZ 2
#define LLEN 2048
#define NHEADS 32
#define HEADDIM 64
#define DSTATE 128
#define DCONV 4
#define DINNER (NHEADS * HEADDIM)                  // 2048
#define DPROJ  (2 * DINNER + 2 * DSTATE + NHEADS)  // 4384
#define Q 256                                      // scan chunk length
#define NCHUNK (LLEN / Q)                          // 8
#define XCW 2304                                   // XC row: [xv 2048 | B 128 | C 128]

__device__ __forceinline__ float sigm(float x) {
    return __builtin_amdgcn_rcpf(1.0f + __expf(-x));
}

// Robust python-int scalar read (int32 bits or float32 bits).
__device__ __forceinline__ float int_scalar(const int* p) {
    int i = *p;
    if (i >= 0 && i <= 1000000) return (float)i;
    return __int_as_float(i);
}

// ---------------------------------------------------------------------------
// Kernel 1: conv+silu for ALL 2304 conv channels -> XC row [xv|B|C], plus
// dt/dA. One block per (b,l); thread handles 8 x-channels + 1 B/C channel.
// ---------------------------------------------------------------------------
__global__ __launch_bounds__(256) void pre_kernel(
    const float* __restrict__ zx, const float* __restrict__ cw,
    const float* __restrict__ cb, const float* __restrict__ dtb,
    const float* __restrict__ alog, const float* __restrict__ dts,
    const int* __restrict__ mn_p, const int* __restrict__ mx_p,
    float* __restrict__ XC, float2* __restrict__ dtA)
{
    const int bl  = blockIdx.x;            // 0 .. B*L-1
    const int b   = bl / LLEN;
    const int l   = bl % LLEN;
    const int tid = threadIdx.x;

    // ---- x channels: 8 per thread (conv rows 0..2047, zx cols DINNER+c) ----
    {
        const int c8 = tid * 8;
        float acc[8];
        {
            float4 b0 = *(const float4*)(cb + c8);
            float4 b1 = *(const float4*)(cb + c8 + 4);
            acc[0]=b0.x; acc[1]=b0.y; acc[2]=b0.z; acc[3]=b0.w;
            acc[4]=b1.x; acc[5]=b1.y; acc[6]=b1.z; acc[7]=b1.w;
        }
        float4 w[8];
        #pragma unroll
        for (int j = 0; j < 8; j++) w[j] = *(const float4*)(cw + (size_t)(c8 + j) * 4);
        #pragma unroll
        for (int k = 0; k < DCONV; k++) {
            const int lk = l - (DCONV - 1) + k;
            if (lk >= 0) {
                const float* xr = zx + ((size_t)b * LLEN + lk) * DPROJ + DINNER + c8;
                float4 v0 = *(const float4*)xr;
                float4 v1 = *(const float4*)(xr + 4);
                const float tap[8] = {v0.x,v0.y,v0.z,v0.w,v1.x,v1.y,v1.z,v1.w};
                #pragma unroll
                for (int j = 0; j < 8; j++) {
                    const float wk = (k==0) ? w[j].x : (k==1) ? w[j].y : (k==2) ? w[j].z : w[j].w;
                    acc[j] += wk * tap[j];
                }
            }
        }
        float r[8];
        #pragma unroll
        for (int j = 0; j < 8; j++) r[j] = acc[j] * sigm(acc[j]);
        float* xo = XC + (size_t)bl * XCW + c8;
        *(float4*)xo       = make_float4(r[0], r[1], r[2], r[3]);
        *(float4*)(xo + 4) = make_float4(r[4], r[5], r[6], r[7]);
    }

    // ---- B/C channel: conv row 2048+tid, zx col 4096+tid ----
    {
        const int ch = 2048 + tid;
        float a = cb[ch];
        const float4 wv = *(const float4*)(cw + (size_t)ch * 4);
        #pragma unroll
        for (int k = 0; k < DCONV; k++) {
            const int lk = l - (DCONV - 1) + k;
            if (lk >= 0) {
                const float wk = (k==0) ? wv.x : (k==1) ? wv.y : (k==2) ? wv.z : wv.w;
                a += wk * zx[((size_t)b * LLEN + lk) * DPROJ + DINNER + ch];
            }
        }
        XC[(size_t)bl * XCW + ch] = a * sigm(a);
    }

    // ---- dt / dA ----
    if (tid < NHEADS) {
        float raw = zx[(size_t)bl * DPROJ + (DPROJ - NHEADS) + tid];
        float v   = raw * dts[tid] + dtb[tid];
        float sp  = (v > 20.0f) ? v : log1pf(__expf(v));
        float dt  = fminf(fmaxf(sp, int_scalar(mn_p)), int_scalar(mx_p));
        float A   = -__expf(alog[tid]);
        dtA[(size_t)bl * NHEADS + tid] = make_float2(dt, __expf(dt * A));
    }
}

// ---------------------------------------------------------------------------
// Kernel 2: per-chunk inclusive decay cumprod cumA[t] and chunk totals dtot.
// ---------------------------------------------------------------------------
__global__ __launch_bounds__(64) void cum_kernel(
    const float2* __restrict__ dtA, float* __restrict__ cumA,
    float* __restrict__ dtot)
{
    const int c = blockIdx.x, h = blockIdx.y, b = blockIdx.z;
    const int lane = threadIdx.x;          // 0..63
    const float2* pd = dtA + ((size_t)(b * LLEN + c * Q + lane * 4)) * NHEADS + h;
    const float a0 = pd[0].y;
    const float a1 = pd[NHEADS].y;
    const float a2 = pd[2 * NHEADS].y;
    const float a3 = pd[3 * NHEADS].y;

    float s = a0 * a1 * a2 * a3;
    #pragma unroll
    for (int off = 1; off < 64; off <<= 1) {
        float v = __shfl_up(s, off, 64);
        if (lane >= off) s *= v;
    }
    float excl = __shfl_up(s, 1, 64);
    if (lane == 0) excl = 1.0f;

    const float c0 = excl * a0, c1 = c0 * a1, c2 = c1 * a2, c3 = c2 * a3;
    float* pc = cumA + ((size_t)(b * NHEADS + h) * NCHUNK + c) * Q + lane * 4;
    *(float4*)pc = make_float4(c0, c1, c2, c3);
    if (lane == 63) dtot[(size_t)(b * NHEADS + h) * NCHUNK + c] = c3;
}

// ---------------------------------------------------------------------------
// Phase A scan: zero-init local chunk scan, 16 n per lane, 8 lanes per p.
// Emits ungated y_pre (into out) and chunk-end local states SA.
// Grid (2*NCHUNK, NHEADS, BSZ) x 256. Wave covers 8 p; ng = lane>>3.
// ---------------------------------------------------------------------------
__global__ __launch_bounds__(256, 4) void scan_kernel(
    const float* __restrict__ XC, const float2* __restrict__ dtA,
    const float* __restrict__ d_param, float* __restrict__ SA,
    float* __restrict__ out)
{
    const int pb   = blockIdx.x & 1;
    const int c    = blockIdx.x >> 1;
    const int h    = blockIdx.y;
    const int b    = blockIdx.z;
    const int tid  = threadIdx.x;
    const int wave = tid >> 6;
    const int lane = tid & 63;
    const int pl   = lane & 7;
    const int ng   = lane >> 3;            // 0..7
    const int p    = pb * 32 + wave * 8 + pl;
    const int n0   = ng * 16;
    const int t0   = c * Q;
    const int cx   = h * HEADDIM + p;
    const float Dh = d_param[h];

    const float* pR = XC + ((size_t)b * LLEN + t0) * XCW;
    const float* pB = pR + 2048 + n0;      // C lives at pB+128 (imm offset)
    const float* pv = pR + cx;
    const float2* pd = dtA + ((size_t)b * LLEN + t0) * NHEADS + h;
    float* pw = out + ((size_t)b * LLEN + t0) * DINNER + cx;

    float st[16];
    #pragma unroll
    for (int j = 0; j < 16; j++) st[j] = 0.0f;

    float4 rb[2][4], rc[2][4]; float rxv[2]; float2 rda[2];
    #pragma unroll
    for (int u = 0; u < 2; u++) {
        const float* r = pB + (size_t)u * XCW;
        rb[u][0] = *(const float4*)(r);
        rb[u][1] = *(const float4*)(r + 4);
        rb[u][2] = *(const float4*)(r + 8);
        rb[u][3] = *(const float4*)(r + 12);
        rc[u][0] = *(const float4*)(r + 128);
        rc[u][1] = *(const float4*)(r + 132);
        rc[u][2] = *(const float4*)(r + 136);
        rc[u][3] = *(const float4*)(r + 140);
        rxv[u] = pv[(size_t)u * XCW];
        rda[u] = pd[(size_t)u * NHEADS];
    }
    const float* pn0 = pB + 2 * XCW;
    const float* pn1 = pB + 3 * XCW;
    const float* pv0 = pv + 2 * XCW;
    const float* pv1 = pv + 3 * XCW;
    const float2* pdn = pd + 2 * NHEADS;

    auto step = [&](int u, bool pf) {
        float Bv[16], Cv[16];
        #pragma unroll
        for (int i = 0; i < 4; i++) {
            Bv[4*i+0]=rb[u][i].x; Bv[4*i+1]=rb[u][i].y; Bv[4*i+2]=rb[u][i].z; Bv[4*i+3]=rb[u][i].w;
            Cv[4*i+0]=rc[u][i].x; Cv[4*i+1]=rc[u][i].y; Cv[4*i+2]=rc[u][i].z; Cv[4*i+3]=rc[u][i].w;
        }
        const float xv = rxv[u];
        const float2 da = rda[u];
        if (pf) {
            const float* r = u ? pn1 : pn0;
            rb[u][0] = *(const float4*)(r);
            rb[u][1] = *(const float4*)(r + 4);
            rb[u][2] = *(const float4*)(r + 8);
            rb[u][3] = *(const float4*)(r + 12);
            rc[u][0] = *(const float4*)(r + 128);
            rc[u][1] = *(const float4*)(r + 132);
            rc[u][2] = *(const float4*)(r + 136);
            rc[u][3] = *(const float4*)(r + 140);
            rxv[u] = u ? pv1[0] : pv0[0];
            rda[u] = pdn[u * NHEADS];
        }
        const float coef = da.x * xv;
        const float dAv  = da.y;
        float a0 = 0.f, a1 = 0.f, a2 = 0.f, a3 = 0.f;
        #pragma unroll
        for (int j = 0; j < 4; j++)  { st[j]    = dAv*st[j]    + coef*Bv[j];    a0 += st[j]   *Cv[j];    }
        #pragma unroll
        for (int j = 0; j < 4; j++)  { st[j+4]  = dAv*st[j+4]  + coef*Bv[j+4];  a1 += st[j+4] *Cv[j+4];  }
        #pragma unroll
        for (int j = 0; j < 4; j++)  { st[j+8]  = dAv*st[j+8]  + coef*Bv[j+8];  a2 += st[j+8] *Cv[j+8];  }
        #pragma unroll
        for (int j = 0; j < 4; j++)  { st[j+12] = dAv*st[j+12] + coef*Bv[j+12]; a3 += st[j+12]*Cv[j+12]; }
        float acc = (a0 + a1) + (a2 + a3);
        acc += __shfl_xor(acc, 8, 64);
        acc += __shfl_xor(acc, 16, 64);
        acc += __shfl_xor(acc, 32, 64);
        if (lane < 8) *pw = acc + Dh * xv;     // ungated y_pre
        pw += DINNER;
    };

    for (int tb = 0; tb < Q - 2; tb += 2) {
        step(0, true);
        step(1, true);
        pn0 += 2 * XCW; pn1 += 2 * XCW;
        pv0 += 2 * XCW; pv1 += 2 * XCW;
        pdn += 2 * NHEADS;
    }
    step(0, false);
    step(1, false);

    const size_t sb = ((size_t)(b * NHEADS + h) * NCHUNK + c) * (HEADDIM * DSTATE)
                    + (size_t)p * DSTATE + n0;
    *(float4*)(SA + sb)      = make_float4(st[0],  st[1],  st[2],  st[3]);
    *(float4*)(SA + sb + 4)  = make_float4(st[4],  st[5],  st[6],  st[7]);
    *(float4*)(SA + sb + 8)  = make_float4(st[8],  st[9],  st[10], st[11]);
    *(float4*)(SA + sb + 12) = make_float4(st[12], st[13], st[14], st[15]);
}

// ---------------------------------------------------------------------------
// Phase B: sequential chunk combine per (b,h). SA[c] := state ENTERING chunk c.
// Grid (NHEADS, BSZ, 4): 4 p-groups for better CU utilization.
// ---------------------------------------------------------------------------
__global__ __launch_bounds__(256) void combine_kernel(
    const float* __restrict__ init_state, const float* __restrict__ dtot,
    float* __restrict__ SA)
{
    const int h = blockIdx.x, b = blockIdx.y, pg = blockIdx.z;
    const size_t hd = (size_t)(b * NHEADS + h);
    const size_t eb = (size_t)pg * 2048 + (size_t)threadIdx.x * 8;

    const float4* pi = (const float4*)(init_state + hd * (HEADDIM * DSTATE) + eb);
    float4 r0 = pi[0], r1 = pi[1];

    for (int c = 0; c < NCHUNK; c++) {
        const float d = dtot[hd * NCHUNK + c];
        float4* ps = (float4*)(SA + (hd * NCHUNK + c) * (size_t)(HEADDIM * DSTATE) + eb);
        float4 l0 = ps[0], l1 = ps[1];
        ps[0] = r0; ps[1] = r1;
        r0.x = d * r0.x + l0.x;  r0.y = d * r0.y + l0.y;
        r0.z = d * r0.z + l0.z;  r0.w = d * r0.w + l0.w;
        r1.x = d * r1.x + l1.x;  r1.y = d * r1.y + l1.y;
        r1.z = d * r1.z + l1.z;  r1.w = d * r1.w + l1.w;
    }
}

// ---------------------------------------------------------------------------
// Phase C: cross-chunk correction as a tiled GEMM + gate epilogue.
//   corr[t,p] = (cumA[t]*C[t,:]) . Sin[p,:]   (K = DSTATE = 128)
//   out[t,p]  = (y_pre[t,p] + corr[t,p]) * silu(z[t,p])
// One block per (b,h,c): 256 threads, 8x8 register tile each (256t x 64p).
// ---------------------------------------------------------------------------
__global__ __launch_bounds__(256, 2) void gate_kernel(
    const float* __restrict__ zx, const float* __restrict__ XC,
    const float* __restrict__ cumA, const float* __restrict__ SA,
    float* __restrict__ out)
{
    __shared__ float sT[DSTATE][HEADDIM];   // Sin^T [n][p], 32 KB
    __shared__ float sC[32][Q];             // scaled C panel [k][t], 32 KB

    const int c = blockIdx.x, h = blockIdx.y, b = blockIdx.z;
    const int tid = threadIdx.x;
    const int tx = tid & 31;                // t-tile: t = tx*8 + i
    const int ty = tid >> 5;                // p-tile: p = ty*8 + j
    const size_t hd = (size_t)(b * NHEADS + h);
    const size_t row0 = (size_t)b * LLEN + c * Q;

    // ---- load Sin^T (transpose SA[p][n] -> sT[n][p]) ----
    {
        const int p  = tid >> 2;
        const int nq = (tid & 3) * 32;
        const float* ps = SA + (hd * NCHUNK + c) * (size_t)(HEADDIM * DSTATE)
                        + (size_t)p * DSTATE + nq;
        #pragma unroll
        for (int i = 0; i < 8; i++) {
            float4 v = *(const float4*)(ps + i * 4);
            const int n = nq + i * 4;
            sT[n][p] = v.x; sT[n+1][p] = v.y; sT[n+2][p] = v.z; sT[n+3][p] = v.w;
        }
    }

    float acc[8][8];
    #pragma unroll
    for (int i = 0; i < 8; i++)
        #pragma unroll
        for (int j = 0; j < 8; j++) acc[i][j] = 0.0f;

    const float* pCbase = XC + row0 * XCW + 2176;           // C columns
    const float* pcm    = cumA + (hd * NCHUNK + c) * Q;

    for (int kp = 0; kp < 4; kp++) {                        // 4 K-panels of 32
        __syncthreads();
        {   // stage cumA-scaled C panel, coalesced in groups of 8 lanes
            const int k4 = (tid & 7) * 4;
            #pragma unroll
            for (int rep = 0; rep < 8; rep++) {
                const int t = (tid >> 3) + rep * 32;
                float4 v = *(const float4*)(pCbase + (size_t)t * XCW + kp * 32 + k4);
                const float cm = pcm[t];
                sC[k4+0][t] = v.x * cm;
                sC[k4+1][t] = v.y * cm;
                sC[k4+2][t] = v.z * cm;
                sC[k4+3][t] = v.w * cm;
            }
        }
        __syncthreads();

        // software-pipelined inner product over the 32 k of this panel
        float avA[8], bvA[8], avB[8], bvB[8];
        *(float4*)&avA[0] = *(const float4*)&sC[0][tx*8];
        *(float4*)&avA[4] = *(const float4*)&sC[0][tx*8+4];
        *(float4*)&bvA[0] = *(const float4*)&sT[kp*32][ty*8];
        *(float4*)&bvA[4] = *(const float4*)&sT[kp*32][ty*8+4];
        for (int k = 0; k < 32; k += 2) {
            *(float4*)&avB[0] = *(const float4*)&sC[k+1][tx*8];
            *(float4*)&avB[4] = *(const float4*)&sC[k+1][tx*8+4];
            *(float4*)&bvB[0] = *(const float4*)&sT[kp*32+k+1][ty*8];
            *(float4*)&bvB[4] = *(const float4*)&sT[kp*32+k+1][ty*8+4];
            #pragma unroll
            for (int i = 0; i < 8; i++)
                #pragma unroll
                for (int j = 0; j < 8; j++) acc[i][j] += avA[i] * bvA[j];
            if (k + 2 < 32) {
                *(float4*)&avA[0] = *(const float4*)&sC[k+2][tx*8];
                *(float4*)&avA[4] = *(const float4*)&sC[k+2][tx*8+4];
                *(float4*)&bvA[0] = *(const float4*)&sT[kp*32+k+2][ty*8];
                *(float4*)&bvA[4] = *(const float4*)&sT[kp*32+k+2][ty*8+4];
            }
            #pragma unroll
            for (int i = 0; i < 8; i++)
                #pragma unroll
                for (int j = 0; j < 8; j++) acc[i][j] += avB[i] * bvB[j];
        }
    }

    // ---- epilogue: out = (y_pre + corr) * silu(z) ----
    #pragma unroll
    for (int i = 0; i < 8; i++) {
        const int t = tx * 8 + i;
        float* po = out + (row0 + t) * (size_t)DINNER + h * HEADDIM + ty * 8;
        const float* pz = zx + (row0 + t) * (size_t)DPROJ + h * HEADDIM + ty * 8;
        float4 y0 = *(const float4*)po;
        float4 y1 = *(const float4*)(po + 4);
        float4 z0 = *(const float4*)pz;
        float4 z1 = *(const float4*)(pz + 4);
        const float yv[8] = {y0.x,y0.y,y0.z,y0.w,y1.x,y1.y,y1.z,y1.w};
        const float zv[8] = {z0.x,z0.y,z0.z,z0.w,z1.x,z1.y,z1.z,z1.w};
        float r[8];
        #pragma unroll
        for (int j = 0; j < 8; j++) {
            const float zg = zv[j] * sigm(zv[j]);
            r[j] = (yv[j] + acc[i][j]) * zg;
        }
        *(float4*)po       = make_float4(r[0], r[1], r[2], r[3]);
        *(float4*)(po + 4) = make_float4(r[4], r[5], r[6], r[7]);
    }
}

// ---------------------------------------------------------------------------
extern "C" void kernel_launch(void* const* d_in, const int* in_sizes, int n_in,
                              void* d_out, int out_size, void* d_ws, size_t ws_size,
                              hipStream_t stream) {
    const float* zxbcdt   = (const float*)d_in[0];
    const float* conv_w   = (const float*)d_in[1];
    const float* conv_b   = (const float*)d_in[2];
    const float* dt_bias  = (const float*)d_in[3];
    const float* a_log    = (const float*)d_in[4];
    const float* d_param  = (const float*)d_in[5];
    const float* dt_scale = (const float*)d_in[6];
    const float* init_st  = (const float*)d_in[7];
    const int* dt_min_p   = (const int*)d_in[11];
    const int* dt_max_p   = (const int*)d_in[12];
    float* out = (float*)d_out;

    // workspace: XC 37.75 + dtA 1 + SA 16.8 + cumA 0.5 MiB + dtot ~= 56.1 MiB
    char* ws = (char*)d_ws;
    const size_t n_bl = (size_t)BSZ * LLEN;                           // 4096
    float*  XC  = (float*)ws;  ws += n_bl * XCW * sizeof(float);      // 37.75 MiB
    float2* dtA = (float2*)ws; ws += n_bl * NHEADS * sizeof(float2);  // 1 MiB
    float*  SA  = (float*)ws;                                         // 16.8 MiB
    ws += (size_t)BSZ * NHEADS * NCHUNK * HEADDIM * DSTATE * sizeof(float);
    float*  dtot = (float*)ws; ws += (size_t)BSZ * NHEADS * NCHUNK * sizeof(float);
    float*  cumA = (float*)ws;                                        // 0.5 MiB
    ws += (size_t)BSZ * NHEADS * LLEN * sizeof(float);

    pre_kernel<<<dim3((unsigned)n_bl), 256, 0, stream>>>(
        zxbcdt, conv_w, conv_b, dt_bias, a_log, dt_scale,
        dt_min_p, dt_max_p, XC, dtA);

    cum_kernel<<<dim3(NCHUNK, NHEADS, BSZ), 64, 0, stream>>>(dtA, cumA, dtot);

    scan_kernel<<<dim3(2 * NCHUNK, NHEADS, BSZ), 256, 0, stream>>>(
        XC, dtA, d_param, SA, out);

    combine_kernel<<<dim3(NHEADS, BSZ, 4), 256, 0, stream>>>(init_st, dtot, SA);

    gate_kernel<<<dim3(NCHUNK, NHEADS, BSZ), 256, 0, stream>>>(
        zxbcdt, XC, cumA, SA, out);
}

// Round 3
// 477.882 us; speedup vs baseline: 1.3984x; 1.0383x over previous
//
#include <hip/hip_runtime.h>
#include <hip/hip_bf16.h>

#define BSZ 2
#define LLEN 2048
#define NHEADS 32
#define HEADDIM 64
#define DSTATE 128
#define DCONV 4
#define DINNER (NHEADS * HEADDIM)                  // 2048
#define DPROJ  (2 * DINNER + 2 * DSTATE + NHEADS)  // 4384
#define Q 256                                      // scan chunk length
#define NCHUNK (LLEN / Q)                          // 8
#define XCW 2304                                   // XC row: [xv 2048 | B 128 | C 128]

__device__ __forceinline__ float sigm(float x) {
    return __builtin_amdgcn_rcpf(1.0f + __expf(-x));
}

// Robust python-int scalar read (int32 bits or float32 bits).
__device__ __forceinline__ float int_scalar(const int* p) {
    int i = *p;
    if (i >= 0 && i <= 1000000) return (float)i;
    return __int_as_float(i);
}

// ---------------------------------------------------------------------------
// Kernel 1: conv+silu for ALL 2304 conv channels -> XC row [xv|B|C], plus
// dt/dA. One block per (b,l); thread handles 8 x-channels + 1 B/C channel.
// ---------------------------------------------------------------------------
__global__ __launch_bounds__(256) void pre_kernel(
    const float* __restrict__ zx, const float* __restrict__ cw,
    const float* __restrict__ cb, const float* __restrict__ dtb,
    const float* __restrict__ alog, const float* __restrict__ dts,
    const int* __restrict__ mn_p, const int* __restrict__ mx_p,
    float* __restrict__ XC, float2* __restrict__ dtA)
{
    const int bl  = blockIdx.x;            // 0 .. B*L-1
    const int b   = bl / LLEN;
    const int l   = bl % LLEN;
    const int tid = threadIdx.x;

    // ---- x channels: 8 per thread (conv rows 0..2047, zx cols DINNER+c) ----
    {
        const int c8 = tid * 8;
        float acc[8];
        {
            float4 b0 = *(const float4*)(cb + c8);
            float4 b1 = *(const float4*)(cb + c8 + 4);
            acc[0]=b0.x; acc[1]=b0.y; acc[2]=b0.z; acc[3]=b0.w;
            acc[4]=b1.x; acc[5]=b1.y; acc[6]=b1.z; acc[7]=b1.w;
        }
        float4 w[8];
        #pragma unroll
        for (int j = 0; j < 8; j++) w[j] = *(const float4*)(cw + (size_t)(c8 + j) * 4);
        #pragma unroll
        for (int k = 0; k < DCONV; k++) {
            const int lk = l - (DCONV - 1) + k;
            if (lk >= 0) {
                const float* xr = zx + ((size_t)b * LLEN + lk) * DPROJ + DINNER + c8;
                float4 v0 = *(const float4*)xr;
                float4 v1 = *(const float4*)(xr + 4);
                const float tap[8] = {v0.x,v0.y,v0.z,v0.w,v1.x,v1.y,v1.z,v1.w};
                #pragma unroll
                for (int j = 0; j < 8; j++) {
                    const float wk = (k==0) ? w[j].x : (k==1) ? w[j].y : (k==2) ? w[j].z : w[j].w;
                    acc[j] += wk * tap[j];
                }
            }
        }
        float r[8];
        #pragma unroll
        for (int j = 0; j < 8; j++) r[j] = acc[j] * sigm(acc[j]);
        float* xo = XC + (size_t)bl * XCW + c8;
        *(float4*)xo       = make_float4(r[0], r[1], r[2], r[3]);
        *(float4*)(xo + 4) = make_float4(r[4], r[5], r[6], r[7]);
    }

    // ---- B/C channel: conv row 2048+tid, zx col 4096+tid ----
    {
        const int ch = 2048 + tid;
        float a = cb[ch];
        const float4 wv = *(const float4*)(cw + (size_t)ch * 4);
        #pragma unroll
        for (int k = 0; k < DCONV; k++) {
            const int lk = l - (DCONV - 1) + k;
            if (lk >= 0) {
                const float wk = (k==0) ? wv.x : (k==1) ? wv.y : (k==2) ? wv.z : wv.w;
                a += wk * zx[((size_t)b * LLEN + lk) * DPROJ + DINNER + ch];
            }
        }
        XC[(size_t)bl * XCW + ch] = a * sigm(a);
    }

    // ---- dt / dA ----
    if (tid < NHEADS) {
        float raw = zx[(size_t)bl * DPROJ + (DPROJ - NHEADS) + tid];
        float v   = raw * dts[tid] + dtb[tid];
        float sp  = (v > 20.0f) ? v : log1pf(__expf(v));
        float dt  = fminf(fmaxf(sp, int_scalar(mn_p)), int_scalar(mx_p));
        float A   = -__expf(alog[tid]);
        dtA[(size_t)bl * NHEADS + tid] = make_float2(dt, __expf(dt * A));
    }
}

// ---------------------------------------------------------------------------
// Kernel 2: per-chunk inclusive decay cumprod cumA[t] and chunk totals dtot.
// ---------------------------------------------------------------------------
__global__ __launch_bounds__(64) void cum_kernel(
    const float2* __restrict__ dtA, float* __restrict__ cumA,
    float* __restrict__ dtot)
{
    const int c = blockIdx.x, h = blockIdx.y, b = blockIdx.z;
    const int lane = threadIdx.x;          // 0..63
    const float2* pd = dtA + ((size_t)(b * LLEN + c * Q + lane * 4)) * NHEADS + h;
    const float a0 = pd[0].y;
    const float a1 = pd[NHEADS].y;
    const float a2 = pd[2 * NHEADS].y;
    const float a3 = pd[3 * NHEADS].y;

    float s = a0 * a1 * a2 * a3;
    #pragma unroll
    for (int off = 1; off < 64; off <<= 1) {
        float v = __shfl_up(s, off, 64);
        if (lane >= off) s *= v;
    }
    float excl = __shfl_up(s, 1, 64);
    if (lane == 0) excl = 1.0f;

    const float c0 = excl * a0, c1 = c0 * a1, c2 = c1 * a2, c3 = c2 * a3;
    float* pc = cumA + ((size_t)(b * NHEADS + h) * NCHUNK + c) * Q + lane * 4;
    *(float4*)pc = make_float4(c0, c1, c2, c3);
    if (lane == 63) dtot[(size_t)(b * NHEADS + h) * NCHUNK + c] = c3;
}

// ---------------------------------------------------------------------------
// Phase A scan: zero-init local chunk scan.
// One block per (b,h,c). Wave: 8 p-slots x 8 n-groups; each lane owns
// p0=wave*8+pl and p0+32, 16 n each. Depth-4 register prefetch ring.
// ng = lane&7 (low bits): coalesced B/C loads + cheap xor-1/2/4 reduce.
// ---------------------------------------------------------------------------
__global__ __launch_bounds__(256, 2) void scan_kernel(
    const float* __restrict__ XC, const float2* __restrict__ dtA,
    const float* __restrict__ d_param, float* __restrict__ SA,
    float* __restrict__ out)
{
    const int c    = blockIdx.x;
    const int h    = blockIdx.y;
    const int b    = blockIdx.z;
    const int tid  = threadIdx.x;
    const int wave = tid >> 6;
    const int lane = tid & 63;
    const int ng   = lane & 7;             // n-group (low bits)
    const int pl   = lane >> 3;            // 0..7
    const int p0   = wave * 8 + pl;        // p_lo in 0..31; p_hi = p0+32
    const int n0   = ng * 16;
    const int t0   = c * Q;
    const int cx   = h * HEADDIM + p0;
    const float Dh = d_param[h];

    const float*  pB = XC + ((size_t)b * LLEN + t0) * XCW + 2048 + n0;  // C at +128
    const float*  pv = XC + ((size_t)b * LLEN + t0) * XCW + cx;         // x_hi at +32
    const float2* pd = dtA + ((size_t)b * LLEN + t0) * NHEADS + h;
    float*        pw = out + ((size_t)b * LLEN + t0) * DINNER + cx;     // hi at +32

    float stl[16], sth[16];
    #pragma unroll
    for (int j = 0; j < 16; j++) { stl[j] = 0.0f; sth[j] = 0.0f; }

    // depth-4 register ring for B,C,x,dtA
    float4 rb[4][4], rc[4][4];
    float  rxl[4], rxh[4];
    float2 rda[4];
    #pragma unroll
    for (int u = 0; u < 4; u++) {
        const float* r = pB + (size_t)u * XCW;
        #pragma unroll
        for (int i = 0; i < 4; i++) rb[u][i] = *(const float4*)(r + i * 4);
        #pragma unroll
        for (int i = 0; i < 4; i++) rc[u][i] = *(const float4*)(r + 128 + i * 4);
        rxl[u] = pv[(size_t)u * XCW];
        rxh[u] = pv[(size_t)u * XCW + 32];
        rda[u] = pd[(size_t)u * NHEADS];
    }
    const float*  pn  = pB + 4 * XCW;      // B/C prefetch row (t+4)
    const float*  pxn = pv + 4 * XCW;      // x prefetch row (t+4)
    const float2* pdn = pd + 4 * NHEADS;

    auto step = [&](int u) {
        float Bv[16], Cv[16];
        #pragma unroll
        for (int i = 0; i < 4; i++) {
            Bv[4*i+0]=rb[u][i].x; Bv[4*i+1]=rb[u][i].y; Bv[4*i+2]=rb[u][i].z; Bv[4*i+3]=rb[u][i].w;
            Cv[4*i+0]=rc[u][i].x; Cv[4*i+1]=rc[u][i].y; Cv[4*i+2]=rc[u][i].z; Cv[4*i+3]=rc[u][i].w;
        }
        const float  xl = rxl[u], xh = rxh[u];
        const float2 da = rda[u];

        // prefetch t+4 into slot u (unconditional; overrun lands in XC pad)
        #pragma unroll
        for (int i = 0; i < 4; i++) rb[u][i] = *(const float4*)(pn + i * 4);
        #pragma unroll
        for (int i = 0; i < 4; i++) rc[u][i] = *(const float4*)(pn + 128 + i * 4);
        rxl[u] = pxn[0];
        rxh[u] = pxn[32];
        rda[u] = pdn[0];
        pn += XCW; pxn += XCW; pdn += NHEADS;

        const float dAv = da.y;
        const float cl  = da.x * xl;
        const float ch  = da.x * xh;
        float al0 = 0.f, al1 = 0.f, ah0 = 0.f, ah1 = 0.f;
        #pragma unroll
        for (int j = 0; j < 8; j++) {
            stl[j] = dAv * stl[j] + cl * Bv[j];  al0 += stl[j] * Cv[j];
            sth[j] = dAv * sth[j] + ch * Bv[j];  ah0 += sth[j] * Cv[j];
        }
        #pragma unroll
        for (int j = 8; j < 16; j++) {
            stl[j] = dAv * stl[j] + cl * Bv[j];  al1 += stl[j] * Cv[j];
            sth[j] = dAv * sth[j] + ch * Bv[j];  ah1 += sth[j] * Cv[j];
        }
        float al = al0 + al1, ah = ah0 + ah1;
        al += __shfl_xor(al, 1, 64);  ah += __shfl_xor(ah, 1, 64);
        al += __shfl_xor(al, 2, 64);  ah += __shfl_xor(ah, 2, 64);
        al += __shfl_xor(al, 4, 64);  ah += __shfl_xor(ah, 4, 64);

        if (ng == 0) pw[0]  = al + Dh * xl;     // ungated y_pre, p_lo
        if (ng == 1) pw[32] = ah + Dh * xh;     // ungated y_pre, p_hi
        pw += DINNER;
    };

    for (int tb = 0; tb < Q; tb += 4) {
        step(0); step(1); step(2); step(3);
    }

    const size_t sb = ((size_t)(b * NHEADS + h) * NCHUNK + c) * (HEADDIM * DSTATE)
                    + (size_t)p0 * DSTATE + n0;
    *(float4*)(SA + sb)      = make_float4(stl[0],  stl[1],  stl[2],  stl[3]);
    *(float4*)(SA + sb + 4)  = make_float4(stl[4],  stl[5],  stl[6],  stl[7]);
    *(float4*)(SA + sb + 8)  = make_float4(stl[8],  stl[9],  stl[10], stl[11]);
    *(float4*)(SA + sb + 12) = make_float4(stl[12], stl[13], stl[14], stl[15]);
    const size_t sh = sb + (size_t)32 * DSTATE;
    *(float4*)(SA + sh)      = make_float4(sth[0],  sth[1],  sth[2],  sth[3]);
    *(float4*)(SA + sh + 4)  = make_float4(sth[4],  sth[5],  sth[6],  sth[7]);
    *(float4*)(SA + sh + 8)  = make_float4(sth[8],  sth[9],  sth[10], sth[11]);
    *(float4*)(SA + sh + 12) = make_float4(sth[12], sth[13], sth[14], sth[15]);
}

// ---------------------------------------------------------------------------
// Phase B: sequential chunk combine per (b,h). SA[c] := state ENTERING chunk c.
// Grid (NHEADS, BSZ, 4): 4 p-groups for better CU utilization.
// ---------------------------------------------------------------------------
__global__ __launch_bounds__(256) void combine_kernel(
    const float* __restrict__ init_state, const float* __restrict__ dtot,
    float* __restrict__ SA)
{
    const int h = blockIdx.x, b = blockIdx.y, pg = blockIdx.z;
    const size_t hd = (size_t)(b * NHEADS + h);
    const size_t eb = (size_t)pg * 2048 + (size_t)threadIdx.x * 8;

    const float4* pi = (const float4*)(init_state + hd * (HEADDIM * DSTATE) + eb);
    float4 r0 = pi[0], r1 = pi[1];

    for (int c = 0; c < NCHUNK; c++) {
        const float d = dtot[hd * NCHUNK + c];
        float4* ps = (float4*)(SA + (hd * NCHUNK + c) * (size_t)(HEADDIM * DSTATE) + eb);
        float4 l0 = ps[0], l1 = ps[1];
        ps[0] = r0; ps[1] = r1;
        r0.x = d * r0.x + l0.x;  r0.y = d * r0.y + l0.y;
        r0.z = d * r0.z + l0.z;  r0.w = d * r0.w + l0.w;
        r1.x = d * r1.x + l1.x;  r1.y = d * r1.y + l1.y;
        r1.z = d * r1.z + l1.z;  r1.w = d * r1.w + l1.w;
    }
}

// ---------------------------------------------------------------------------
// Phase C: cross-chunk correction as a tiled GEMM + gate epilogue.
//   corr[t,p] = (cumA[t]*C[t,:]) . Sin[p,:]   (K = DSTATE = 128)
//   out[t,p]  = (y_pre[t,p] + corr[t,p]) * silu(z[t,p])
// One block per (b,h,c): 256 threads, 8x8 register tile each (256t x 64p).
// ---------------------------------------------------------------------------
__global__ __launch_bounds__(256, 2) void gate_kernel(
    const float* __restrict__ zx, const float* __restrict__ XC,
    const float* __restrict__ cumA, const float* __restrict__ SA,
    float* __restrict__ out)
{
    __shared__ float sT[DSTATE][HEADDIM];   // Sin^T [n][p], 32 KB
    __shared__ float sC[32][Q];             // scaled C panel [k][t], 32 KB

    const int c = blockIdx.x, h = blockIdx.y, b = blockIdx.z;
    const int tid = threadIdx.x;
    const int tx = tid & 31;                // t-tile: t = tx*8 + i
    const int ty = tid >> 5;                // p-tile: p = ty*8 + j
    const size_t hd = (size_t)(b * NHEADS + h);
    const size_t row0 = (size_t)b * LLEN + c * Q;

    // ---- load Sin^T (transpose SA[p][n] -> sT[n][p]) ----
    {
        const int p  = tid >> 2;
        const int nq = (tid & 3) * 32;
        const float* ps = SA + (hd * NCHUNK + c) * (size_t)(HEADDIM * DSTATE)
                        + (size_t)p * DSTATE + nq;
        #pragma unroll
        for (int i = 0; i < 8; i++) {
            float4 v = *(const float4*)(ps + i * 4);
            const int n = nq + i * 4;
            sT[n][p] = v.x; sT[n+1][p] = v.y; sT[n+2][p] = v.z; sT[n+3][p] = v.w;
        }
    }

    float acc[8][8];
    #pragma unroll
    for (int i = 0; i < 8; i++)
        #pragma unroll
        for (int j = 0; j < 8; j++) acc[i][j] = 0.0f;

    const float* pCbase = XC + row0 * XCW + 2176;           // C columns
    const float* pcm    = cumA + (hd * NCHUNK + c) * Q;

    for (int kp = 0; kp < 4; kp++) {                        // 4 K-panels of 32
        __syncthreads();
        {   // stage cumA-scaled C panel, coalesced in groups of 8 lanes
            const int k4 = (tid & 7) * 4;
            #pragma unroll
            for (int rep = 0; rep < 8; rep++) {
                const int t = (tid >> 3) + rep * 32;
                float4 v = *(const float4*)(pCbase + (size_t)t * XCW + kp * 32 + k4);
                const float cm = pcm[t];
                sC[k4+0][t] = v.x * cm;
                sC[k4+1][t] = v.y * cm;
                sC[k4+2][t] = v.z * cm;
                sC[k4+3][t] = v.w * cm;
            }
        }
        __syncthreads();

        // software-pipelined inner product over the 32 k of this panel
        float avA[8], bvA[8], avB[8], bvB[8];
        *(float4*)&avA[0] = *(const float4*)&sC[0][tx*8];
        *(float4*)&avA[4] = *(const float4*)&sC[0][tx*8+4];
        *(float4*)&bvA[0] = *(const float4*)&sT[kp*32][ty*8];
        *(float4*)&bvA[4] = *(const float4*)&sT[kp*32][ty*8+4];
        for (int k = 0; k < 32; k += 2) {
            *(float4*)&avB[0] = *(const float4*)&sC[k+1][tx*8];
            *(float4*)&avB[4] = *(const float4*)&sC[k+1][tx*8+4];
            *(float4*)&bvB[0] = *(const float4*)&sT[kp*32+k+1][ty*8];
            *(float4*)&bvB[4] = *(const float4*)&sT[kp*32+k+1][ty*8+4];
            #pragma unroll
            for (int i = 0; i < 8; i++)
                #pragma unroll
                for (int j = 0; j < 8; j++) acc[i][j] += avA[i] * bvA[j];
            if (k + 2 < 32) {
                *(float4*)&avA[0] = *(const float4*)&sC[k+2][tx*8];
                *(float4*)&avA[4] = *(const float4*)&sC[k+2][tx*8+4];
                *(float4*)&bvA[0] = *(const float4*)&sT[kp*32+k+2][ty*8];
                *(float4*)&bvA[4] = *(const float4*)&sT[kp*32+k+2][ty*8+4];
            }
            #pragma unroll
            for (int i = 0; i < 8; i++)
                #pragma unroll
                for (int j = 0; j < 8; j++) acc[i][j] += avB[i] * bvB[j];
        }
    }

    // ---- epilogue: out = (y_pre + corr) * silu(z) ----
    #pragma unroll
    for (int i = 0; i < 8; i++) {
        const int t = tx * 8 + i;
        float* po = out + (row0 + t) * (size_t)DINNER + h * HEADDIM + ty * 8;
        const float* pz = zx + (row0 + t) * (size_t)DPROJ + h * HEADDIM + ty * 8;
        float4 y0 = *(const float4*)po;
        float4 y1 = *(const float4*)(po + 4);
        float4 z0 = *(const float4*)pz;
        float4 z1 = *(const float4*)(pz + 4);
        const float yv[8] = {y0.x,y0.y,y0.z,y0.w,y1.x,y1.y,y1.z,y1.w};
        const float zv[8] = {z0.x,z0.y,z0.z,z0.w,z1.x,z1.y,z1.z,z1.w};
        float r[8];
        #pragma unroll
        for (int j = 0; j < 8; j++) {
            const float zg = zv[j] * sigm(zv[j]);
            r[j] = (yv[j] + acc[i][j]) * zg;
        }
        *(float4*)po       = make_float4(r[0], r[1], r[2], r[3]);
        *(float4*)(po + 4) = make_float4(r[4], r[5], r[6], r[7]);
    }
}

// ---------------------------------------------------------------------------
extern "C" void kernel_launch(void* const* d_in, const int* in_sizes, int n_in,
                              void* d_out, int out_size, void* d_ws, size_t ws_size,
                              hipStream_t stream) {
    const float* zxbcdt   = (const float*)d_in[0];
    const float* conv_w   = (const float*)d_in[1];
    const float* conv_b   = (const float*)d_in[2];
    const float* dt_bias  = (const float*)d_in[3];
    const float* a_log    = (const float*)d_in[4];
    const float* d_param  = (const float*)d_in[5];
    const float* dt_scale = (const float*)d_in[6];
    const float* init_st  = (const float*)d_in[7];
    const int* dt_min_p   = (const int*)d_in[11];
    const int* dt_max_p   = (const int*)d_in[12];
    float* out = (float*)d_out;

    // workspace: XC (pad +4 rows) 37.8 + dtA 1 + SA 16.8 + cumA 0.5 MiB ~= 56.2 MiB
    char* ws = (char*)d_ws;
    const size_t n_bl = (size_t)BSZ * LLEN;                           // 4096
    float*  XC  = (float*)ws;  ws += (n_bl + 4) * XCW * sizeof(float);
    float2* dtA = (float2*)ws; ws += n_bl * NHEADS * sizeof(float2);
    float*  SA  = (float*)ws;
    ws += (size_t)BSZ * NHEADS * NCHUNK * HEADDIM * DSTATE * sizeof(float);
    float*  dtot = (float*)ws; ws += (size_t)BSZ * NHEADS * NCHUNK * sizeof(float);
    float*  cumA = (float*)ws;
    ws += (size_t)BSZ * NHEADS * LLEN * sizeof(float);

    pre_kernel<<<dim3((unsigned)n_bl), 256, 0, stream>>>(
        zxbcdt, conv_w, conv_b, dt_bias, a_log, dt_scale,
        dt_min_p, dt_max_p, XC, dtA);

    cum_kernel<<<dim3(NCHUNK, NHEADS, BSZ), 64, 0, stream>>>(dtA, cumA, dtot);

    scan_kernel<<<dim3(NCHUNK, NHEADS, BSZ), 256, 0, stream>>>(
        XC, dtA, d_param, SA, out);

    combine_kernel<<<dim3(NHEADS, BSZ, 4), 256, 0, stream>>>(init_st, dtot, SA);

    gate_kernel<<<dim3(NCHUNK, NHEADS, BSZ), 256, 0, stream>>>(
        zxbcdt, XC, cumA, SA, out);
}